// Round 2
// baseline (225.189 us; speedup 1.0000x reference)
//
#include <hip/hip_runtime.h>
#include <hip/hip_bf16.h>

#define NNODES   163842
#define INF      32
#define OUTF     64
#define NPOS     25
#define KTOT     800      // 25*32
#define MT       64       // nodes per block (4 waves x 16 nodes)
#define NTHREADS 256

typedef float  f32x4  __attribute__((ext_vector_type(4)));
typedef __bf16 bf16x8 __attribute__((ext_vector_type(8)));
typedef __bf16 bf16x4 __attribute__((ext_vector_type(4)));

// ---------------- precompute: cast x and W to bf16 into workspace ----------------
__global__ void cvt_kernel(const float* __restrict__ x, const float* __restrict__ W,
                           __bf16* __restrict__ xb, __bf16* __restrict__ wb) {
    int tid = blockIdx.x * blockDim.x + threadIdx.x;
    int stride = gridDim.x * blockDim.x;
    const f32x4* x4 = (const f32x4*)x;
    bf16x4* xb4 = (bf16x4*)xb;
    const int nx4 = NNODES * INF / 4;
    for (int j = tid; j < nx4; j += stride) {
        f32x4 v = x4[j];
        bf16x4 o;
        #pragma unroll
        for (int k = 0; k < 4; ++k) o[k] = (__bf16)v[k];
        xb4[j] = o;
    }
    const f32x4* w4 = (const f32x4*)W;
    bf16x4* wb4 = (bf16x4*)wb;
    const int nw4 = OUTF * KTOT / 4;
    for (int j = tid; j < nw4; j += stride) {
        f32x4 v = w4[j];
        bf16x4 o;
        #pragma unroll
        for (int k = 0; k < 4; ++k) o[k] = (__bf16)v[k];
        wb4[j] = o;
    }
}

// ---------------- fused gather + MFMA, no LDS, no barriers ----------------
// Per wave: 16 nodes. Lane l gathers node base+(l&15), channels 8*(l>>4)..+8.
// That IS the 16x16x32 MFMA A-fragment layout, so gathered vectors feed MFMA
// directly from VGPRs. 5 positions per group, loads-first for 15-deep MLP,
// A/B register double-buffer for next-group index prefetch.
__launch_bounds__(NTHREADS)
__global__ void conv_mfma(const int* __restrict__ nidx, const float* __restrict__ nwt,
                          const __bf16* __restrict__ xb, const __bf16* __restrict__ wb,
                          const float* __restrict__ bias, float* __restrict__ out) {
    const int tid  = threadIdx.x;
    const int lane = tid & 63;
    const int wave = tid >> 6;
    const int arow = lane & 15;      // node within wave / A row / W row offset
    const int kgrp = lane >> 4;      // 0..3 -> channel chunk
    const int gc   = kgrp * 8;
    const int base = blockIdx.x * MT + wave * 16;
    const int node = min(base + arow, NNODES - 1);
    const long ibase = (long)node * 75;

    f32x4 acc[4] = {{0,0,0,0},{0,0,0,0},{0,0,0,0},{0,0,0,0}};

    int ia[15], ib[15];

    auto loadidx = [&](int g, int (&ii)[15]) {
        #pragma unroll
        for (int i = 0; i < 15; ++i) ii[i] = nidx[ibase + g * 15 + i];
    };

    auto dogroup = [&](int g, const int (&ii)[15]) {
        bf16x8 v[15];
        float  w[15];
        #pragma unroll
        for (int t = 0; t < 15; ++t)
            v[t] = *(const bf16x8*)(xb + (long)ii[t] * INF + gc);
        #pragma unroll
        for (int t = 0; t < 15; ++t)
            w[t] = nwt[ibase + g * 15 + t];
        #pragma unroll
        for (int p = 0; p < 5; ++p) {
            bf16x8 af;
            #pragma unroll
            for (int j = 0; j < 8; ++j)
                af[j] = (__bf16)(w[p*3+0] * (float)v[p*3+0][j]
                               + w[p*3+1] * (float)v[p*3+1][j]
                               + w[p*3+2] * (float)v[p*3+2][j]);
            const int koff = (g * 5 + p) * INF + gc;
            #pragma unroll
            for (int nb = 0; nb < 4; ++nb) {
                bf16x8 bw = *(const bf16x8*)(wb + (16*nb + arow) * KTOT + koff);
                acc[nb] = __builtin_amdgcn_mfma_f32_16x16x32_bf16(af, bw, acc[nb], 0, 0, 0);
            }
        }
    };

    loadidx(0, ia);
    loadidx(1, ib);
    dogroup(0, ia);
    loadidx(2, ia);
    dogroup(1, ib);
    loadidx(3, ib);
    dogroup(2, ia);
    loadidx(4, ia);
    dogroup(3, ib);
    dogroup(4, ia);

    // ---- epilogue: D layout col=lane&15, row=4*(lane>>4)+reg (m89-verified) ----
    #pragma unroll
    for (int nb = 0; nb < 4; ++nb) {
        const int col = 16*nb + arow;
        const float bv = bias[col];
        #pragma unroll
        for (int r = 0; r < 4; ++r) {
            const int row = base + 4*kgrp + r;
            if (row < NNODES) out[(long)row * OUTF + col] = acc[nb][r] + bv;
        }
    }
}

// ---------------- safety fallback (no workspace needed), fp32 ----------------
__global__ void conv_fallback(const float* __restrict__ x, const int* __restrict__ nidx,
                              const float* __restrict__ nwt, const float* __restrict__ W,
                              const float* __restrict__ bias, float* __restrict__ out) {
    __shared__ float feat[KTOT];
    const int n = blockIdx.x;
    const int t = threadIdx.x;   // 64
    for (int e = t; e < KTOT; e += 64) {
        const int p = e >> 5, c = e & 31;
        const int ib = n * 75 + p * 3;
        float a = 0.0f;
        #pragma unroll
        for (int v = 0; v < 3; ++v)
            a += nwt[ib+v] * x[nidx[ib+v] * INF + c];
        feat[e] = a;
    }
    __syncthreads();
    float a = bias[t];
    const float* wr = W + t * KTOT;
    for (int k = 0; k < KTOT; ++k) a += feat[k] * wr[k];
    out[(long)n * OUTF + t] = a;
}

extern "C" void kernel_launch(void* const* d_in, const int* in_sizes, int n_in,
                              void* d_out, int out_size, void* d_ws, size_t ws_size,
                              hipStream_t stream) {
    const float* x    = (const float*)d_in[0];
    const int*   nidx = (const int*)  d_in[1];
    const float* nwt  = (const float*)d_in[2];
    const float* W    = (const float*)d_in[3];
    const float* bias = (const float*)d_in[4];
    float* out = (float*)d_out;

    const size_t need = (size_t)NNODES * INF * 2 + (size_t)OUTF * KTOT * 2;
    if (ws_size < need) {
        conv_fallback<<<NNODES, 64, 0, stream>>>(x, nidx, nwt, W, bias, out);
        return;
    }

    __bf16* xb = (__bf16*)d_ws;
    __bf16* wb = xb + (size_t)NNODES * INF;

    cvt_kernel<<<1024, NTHREADS, 0, stream>>>(x, W, xb, wb);
    const int nblocks = (NNODES + MT - 1) / MT;   // 2561
    conv_mfma<<<nblocks, NTHREADS, 0, stream>>>(nidx, nwt, xb, wb, bias, out);
}

// Round 3
// 183.459 us; speedup vs baseline: 1.2275x; 1.2275x over previous
//
#include <hip/hip_runtime.h>
#include <hip/hip_bf16.h>

#define NNODES   163842
#define INF      32
#define OUTF     64
#define NPOS     25
#define KTOT     800      // 25*32
#define MT       64       // nodes per block (4 waves x 16 nodes)
#define NTHREADS 256

typedef float  f32x4  __attribute__((ext_vector_type(4)));
typedef __bf16 bf16x8 __attribute__((ext_vector_type(8)));
typedef __bf16 bf16x4 __attribute__((ext_vector_type(4)));

// ---------------- precompute: cast x and W to bf16 into workspace ----------------
__global__ void cvt_kernel(const float* __restrict__ x, const float* __restrict__ W,
                           __bf16* __restrict__ xb, __bf16* __restrict__ wb) {
    int tid = blockIdx.x * blockDim.x + threadIdx.x;
    int stride = gridDim.x * blockDim.x;
    const f32x4* x4 = (const f32x4*)x;
    bf16x4* xb4 = (bf16x4*)xb;
    const int nx4 = NNODES * INF / 4;
    for (int j = tid; j < nx4; j += stride) {
        f32x4 v = x4[j];
        bf16x4 o;
        #pragma unroll
        for (int k = 0; k < 4; ++k) o[k] = (__bf16)v[k];
        xb4[j] = o;
    }
    const f32x4* w4 = (const f32x4*)W;
    bf16x4* wb4 = (bf16x4*)wb;
    const int nw4 = OUTF * KTOT / 4;
    for (int j = tid; j < nw4; j += stride) {
        f32x4 v = w4[j];
        bf16x4 o;
        #pragma unroll
        for (int k = 0; k < 4; ++k) o[k] = (__bf16)v[k];
        wb4[j] = o;
    }
}

// ---------------- fused gather + MFMA ----------------
// idx+wts staged coalesced in LDS (one barrier). Gathered bf16x8 vectors ARE
// the 16x16x32 MFMA A-fragments (lane l = node l&15, chans 8*(l>>4)), so the
// gather feeds MFMA straight from VGPRs. Double-buffered groups of 5
// positions (15 gathers each) keep 15-30 gathers in flight; launch_bounds
// (.,1) relaxes the reg-pressure target so the compiler keeps them live.
__launch_bounds__(NTHREADS, 1)
__global__ void conv_mfma(const int* __restrict__ nidx, const float* __restrict__ nwt,
                          const __bf16* __restrict__ xb, const __bf16* __restrict__ wb,
                          const float* __restrict__ bias, float* __restrict__ out) {
    __shared__ int   idxs[MT * 75];                  // 19200 B
    __shared__ float wts [MT * 75];                  // 19200 B

    const int tid = threadIdx.x;
    const int blk = blockIdx.x;

    // stage this block's indices + weights, fully coalesced
    {
        const long gbase = (long)blk * (MT * 75);
        const long tot   = (long)NNODES * 75;
        #pragma unroll
        for (int it = 0; it < (MT * 75 + NTHREADS - 1) / NTHREADS; ++it) {
            int i = tid + it * NTHREADS;
            if (i < MT * 75) {
                long g = gbase + i;
                bool ok = g < tot;
                idxs[i] = ok ? nidx[g] : 0;
                wts [i] = ok ? nwt [g] : 0.0f;
            }
        }
    }

    const int lane = tid & 63;
    const int wave = tid >> 6;
    const int arow = lane & 15;      // node within wave / A row / W row offset
    const int kgrp = lane >> 4;      // 0..3 -> channel chunk
    const int gc   = kgrp * 8;
    const int lrow = (wave * 16 + arow) * 75;
    const int base = blk * MT + wave * 16;

    __syncthreads();

    f32x4 acc[4] = {{0,0,0,0},{0,0,0,0},{0,0,0,0},{0,0,0,0}};
    bf16x8 va[15], vb[15];

    auto GATHER = [&](bf16x8 (&v)[15], int g) {
        #pragma unroll
        for (int t = 0; t < 15; ++t) {
            const int idx = idxs[lrow + g * 15 + t];
            v[t] = *(const bf16x8*)(xb + (long)idx * INF + gc);
        }
    };

    auto COMPUTE = [&](const bf16x8 (&v)[15], int g) {
        float w[15];
        #pragma unroll
        for (int t = 0; t < 15; ++t) w[t] = wts[lrow + g * 15 + t];
        #pragma unroll
        for (int p = 0; p < 5; ++p) {
            bf16x8 af;
            #pragma unroll
            for (int j = 0; j < 8; ++j)
                af[j] = (__bf16)(w[p*3+0] * (float)v[p*3+0][j]
                               + w[p*3+1] * (float)v[p*3+1][j]
                               + w[p*3+2] * (float)v[p*3+2][j]);
            const int koff = (g * 5 + p) * INF + gc;
            #pragma unroll
            for (int nb = 0; nb < 4; ++nb) {
                bf16x8 bw = *(const bf16x8*)(wb + (16*nb + arow) * KTOT + koff);
                acc[nb] = __builtin_amdgcn_mfma_f32_16x16x32_bf16(af, bw, acc[nb], 0, 0, 0);
            }
        }
    };

    GATHER(va, 0);
    GATHER(vb, 1);          // 30 gathers in flight before first compute
    COMPUTE(va, 0);
    GATHER(va, 2);
    COMPUTE(vb, 1);
    GATHER(vb, 3);
    COMPUTE(va, 2);
    GATHER(va, 4);
    COMPUTE(vb, 3);
    COMPUTE(va, 4);

    // ---- epilogue: D layout col=lane&15, row=4*(lane>>4)+reg (m89-verified) ----
    #pragma unroll
    for (int nb = 0; nb < 4; ++nb) {
        const int col = 16*nb + arow;
        const float bv = bias[col];
        #pragma unroll
        for (int r = 0; r < 4; ++r) {
            const int row = base + 4*kgrp + r;
            if (row < NNODES) out[(long)row * OUTF + col] = acc[nb][r] + bv;
        }
    }
}

// ---------------- safety fallback (no workspace needed), fp32 ----------------
__global__ void conv_fallback(const float* __restrict__ x, const int* __restrict__ nidx,
                              const float* __restrict__ nwt, const float* __restrict__ W,
                              const float* __restrict__ bias, float* __restrict__ out) {
    __shared__ float feat[KTOT];
    const int n = blockIdx.x;
    const int t = threadIdx.x;   // 64
    for (int e = t; e < KTOT; e += 64) {
        const int p = e >> 5, c = e & 31;
        const int ib = n * 75 + p * 3;
        float a = 0.0f;
        #pragma unroll
        for (int v = 0; v < 3; ++v)
            a += nwt[ib+v] * x[nidx[ib+v] * INF + c];
        feat[e] = a;
    }
    __syncthreads();
    float a = bias[t];
    const float* wr = W + t * KTOT;
    for (int k = 0; k < KTOT; ++k) a += feat[k] * wr[k];
    out[(long)n * OUTF + t] = a;
}

extern "C" void kernel_launch(void* const* d_in, const int* in_sizes, int n_in,
                              void* d_out, int out_size, void* d_ws, size_t ws_size,
                              hipStream_t stream) {
    const float* x    = (const float*)d_in[0];
    const int*   nidx = (const int*)  d_in[1];
    const float* nwt  = (const float*)d_in[2];
    const float* W    = (const float*)d_in[3];
    const float* bias = (const float*)d_in[4];
    float* out = (float*)d_out;

    const size_t need = (size_t)NNODES * INF * 2 + (size_t)OUTF * KTOT * 2;
    if (ws_size < need) {
        conv_fallback<<<NNODES, 64, 0, stream>>>(x, nidx, nwt, W, bias, out);
        return;
    }

    __bf16* xb = (__bf16*)d_ws;
    __bf16* wb = xb + (size_t)NNODES * INF;

    cvt_kernel<<<1024, NTHREADS, 0, stream>>>(x, W, xb, wb);
    const int nblocks = (NNODES + MT - 1) / MT;   // 2561
    conv_mfma<<<nblocks, NTHREADS, 0, stream>>>(nidx, nwt, xb, wb, bias, out);
}

// Round 4
// 179.345 us; speedup vs baseline: 1.2556x; 1.0229x over previous
//
#include <hip/hip_runtime.h>
#include <hip/hip_bf16.h>
#include <type_traits>

#define NNODES   163842
#define INF      32
#define OUTF     64
#define NPOS     25
#define KTOT     800
#define MT       64       // nodes per block (4 waves x 16 nodes)
#define NTHREADS 256

typedef float    f32x4 __attribute__((ext_vector_type(4)));
typedef _Float16 f16x8 __attribute__((ext_vector_type(8)));

// ---------------- precompute: xh = f16(x); wh = per-lane-swizzled f16 W ----------------
// wh layout: frag f = (p*4+nb), lane l, elem j:
//   wh[(f*64 + l)*8 + j] = W[16*nb + (l&15)][p*32 + (l>>4)*8 + j]
// so a wave's B-frag load for (p,nb) is one contiguous coalesced 1KB read.
__global__ void cvt_kernel(const float* __restrict__ x, const float* __restrict__ W,
                           _Float16* __restrict__ xh, _Float16* __restrict__ wh) {
    int tid = blockIdx.x * blockDim.x + threadIdx.x;
    int stride = gridDim.x * blockDim.x;
    const int nx8 = NNODES * INF / 8;          // 655,368
    const f32x4* x4 = (const f32x4*)x;
    f16x8* xh8 = (f16x8*)xh;
    for (int j = tid; j < nx8; j += stride) {
        f32x4 a = x4[2*j], b = x4[2*j+1];
        f16x8 o;
        #pragma unroll
        for (int k = 0; k < 4; ++k) { o[k] = (_Float16)a[k]; o[4+k] = (_Float16)b[k]; }
        xh8[j] = o;
    }
    f16x8* wh8 = (f16x8*)wh;
    for (int t = tid; t < NPOS * 4 * 64; t += stride) {   // 6400 frags-lanes
        const int l  = t & 63;
        const int nb = (t >> 6) & 3;
        const int p  = t >> 8;
        const int row = 16*nb + (l & 15);
        const int kb  = p*32 + (l >> 4)*8;
        const float* src = W + row * KTOT + kb;
        f16x8 o;
        #pragma unroll
        for (int j = 0; j < 8; ++j) o[j] = (_Float16)src[j];
        wh8[t] = o;
    }
}

// ---------------- fused gather + MFMA, software-pipelined ----------------
__launch_bounds__(NTHREADS, 2)
__global__ void conv_mfma(const int* __restrict__ nidx, const float* __restrict__ nwt,
                          const _Float16* __restrict__ xh, const _Float16* __restrict__ wh,
                          const float* __restrict__ bias, float* __restrict__ out) {
    __shared__ int      idxs[MT * 75];     // 19200 B
    __shared__ _Float16 wtsl[MT * 76];     // 9728 B (pad 76 for banks)

    const int tid = threadIdx.x;
    const int blk = blockIdx.x;

    // stage idx + weights (f32->f16), coalesced, zero-fill past NNODES
    {
        const long gbase = (long)blk * (MT * 75);
        const long tot   = (long)NNODES * 75;
        #pragma unroll
        for (int it = 0; it < (MT * 75 + NTHREADS - 1) / NTHREADS; ++it) {
            int i = tid + it * NTHREADS;
            if (i < MT * 75) {
                long g = gbase + i;
                bool ok = g < tot;
                int n = i / 75, t = i % 75;
                idxs[i] = ok ? nidx[g] : 0;
                wtsl[n * 76 + t] = ok ? (_Float16)nwt[g] : (_Float16)0.0f;
            }
        }
    }

    const int lane = tid & 63;
    const int wave = tid >> 6;
    const int arow = lane & 15;       // node within wave's 16
    const int kgrp = lane >> 4;       // channel octet
    const int irow = (wave * 16 + arow) * 75;
    const int wrow = (wave * 16 + arow) * 76;
    const int node0 = blk * MT + wave * 16;
    const _Float16* xg = xh + kgrp * 8;

    __syncthreads();

    f32x4 acc[4] = {{0,0,0,0},{0,0,0,0},{0,0,0,0},{0,0,0,0}};
    f16x8 gA[9], gB[9];      // gather double-buffer (3 pos x 3 verts)
    f16x8 bA[12], bB[12];    // B-frag double-buffer (3 pos x 4 nb)

    #define SB() __builtin_amdgcn_sched_barrier(0)

    auto BLD = [&](f16x8* b, int g, auto CNT) {
        constexpr int C = decltype(CNT)::value;
        #pragma unroll
        for (int q = 0; q < 4 * C; ++q) {
            const int f = g * 12 + q;            // (g*3+p)*4+nb
            b[q] = *(const f16x8*)(wh + (long)f * 512 + lane * 8);
        }
    };
    auto GATH = [&](f16x8* v, int g, auto CNT) {
        constexpr int C = decltype(CNT)::value;
        #pragma unroll
        for (int t = 0; t < 3 * C; ++t) {
            const int idx = idxs[irow + g * 9 + t];
            v[t] = *(const f16x8*)(xg + (long)idx * INF);
        }
    };
    auto COMP = [&](const f16x8* v, const f16x8* b, int g, auto CNT) {
        constexpr int C = decltype(CNT)::value;
        #pragma unroll
        for (int p = 0; p < C; ++p) {
            const int pos = g * 3 + p;
            const _Float16 w0 = wtsl[wrow + pos*3 + 0];
            const _Float16 w1 = wtsl[wrow + pos*3 + 1];
            const _Float16 w2 = wtsl[wrow + pos*3 + 2];
            f16x8 af = v[p*3+0] * w0 + v[p*3+1] * w1 + v[p*3+2] * w2;
            #pragma unroll
            for (int nb = 0; nb < 4; ++nb)
                acc[nb] = __builtin_amdgcn_mfma_f32_16x16x32_f16(b[p*4+nb], af, acc[nb], 0, 0, 0);
        }
    };

    constexpr std::integral_constant<int,3> C3{};
    constexpr std::integral_constant<int,1> C1{};

    BLD(bA,0,C3); GATH(gA,0,C3); SB();
    BLD(bB,1,C3); GATH(gB,1,C3); SB();
    COMP(gA,bA,0,C3); SB(); BLD(bA,2,C3); GATH(gA,2,C3); SB();
    COMP(gB,bB,1,C3); SB(); BLD(bB,3,C3); GATH(gB,3,C3); SB();
    COMP(gA,bA,2,C3); SB(); BLD(bA,4,C3); GATH(gA,4,C3); SB();
    COMP(gB,bB,3,C3); SB(); BLD(bB,5,C3); GATH(gB,5,C3); SB();
    COMP(gA,bA,4,C3); SB(); BLD(bA,6,C3); GATH(gA,6,C3); SB();
    COMP(gB,bB,5,C3); SB(); BLD(bB,7,C3); GATH(gB,7,C3); SB();
    COMP(gA,bA,6,C3); SB(); BLD(bA,8,C1); GATH(gA,8,C1); SB();
    COMP(gB,bB,7,C3); SB();
    COMP(gA,bA,8,C1);

    // epilogue: swapped-operand D = [outcol][node]: col(lane&15)=node,
    // row 4*kgrp+r = outcol within nb block -> f32x4 store per nb
    const int node = node0 + arow;
    if (node < NNODES) {
        #pragma unroll
        for (int nb = 0; nb < 4; ++nb) {
            const int cb = 16*nb + 4*kgrp;
            const f32x4 b4 = *(const f32x4*)(bias + cb);
            f32x4 o;
            #pragma unroll
            for (int r = 0; r < 4; ++r) o[r] = acc[nb][r] + b4[r];
            *(f32x4*)(out + (long)node * OUTF + cb) = o;
        }
    }
    #undef SB
}

// ---------------- safety fallback (no workspace needed), fp32 ----------------
__global__ void conv_fallback(const float* __restrict__ x, const int* __restrict__ nidx,
                              const float* __restrict__ nwt, const float* __restrict__ W,
                              const float* __restrict__ bias, float* __restrict__ out) {
    __shared__ float feat[KTOT];
    const int n = blockIdx.x;
    const int t = threadIdx.x;   // 64
    for (int e = t; e < KTOT; e += 64) {
        const int p = e >> 5, c = e & 31;
        const int ib = n * 75 + p * 3;
        float a = 0.0f;
        #pragma unroll
        for (int v = 0; v < 3; ++v)
            a += nwt[ib+v] * x[nidx[ib+v] * INF + c];
        feat[e] = a;
    }
    __syncthreads();
    float a = bias[t];
    const float* wr = W + t * KTOT;
    for (int k = 0; k < KTOT; ++k) a += feat[k] * wr[k];
    out[(long)n * OUTF + t] = a;
}

extern "C" void kernel_launch(void* const* d_in, const int* in_sizes, int n_in,
                              void* d_out, int out_size, void* d_ws, size_t ws_size,
                              hipStream_t stream) {
    const float* x    = (const float*)d_in[0];
    const int*   nidx = (const int*)  d_in[1];
    const float* nwt  = (const float*)d_in[2];
    const float* W    = (const float*)d_in[3];
    const float* bias = (const float*)d_in[4];
    float* out = (float*)d_out;

    const size_t need = (size_t)NNODES * INF * 2 + (size_t)NPOS * 4 * 64 * 8 * 2;
    if (ws_size < need) {
        conv_fallback<<<NNODES, 64, 0, stream>>>(x, nidx, nwt, W, bias, out);
        return;
    }

    _Float16* xh = (_Float16*)d_ws;
    _Float16* wh = xh + (size_t)NNODES * INF;

    cvt_kernel<<<1024, NTHREADS, 0, stream>>>(x, W, xh, wh);
    const int nblocks = (NNODES + MT - 1) / MT;   // 2561
    conv_mfma<<<nblocks, NTHREADS, 0, stream>>>(nidx, nwt, xh, wh, bias, out);
}

// Round 5
// 177.808 us; speedup vs baseline: 1.2665x; 1.0086x over previous
//
#include <hip/hip_runtime.h>
#include <hip/hip_bf16.h>
#include <type_traits>

#define NNODES   163842
#define INF      32
#define OUTF     64
#define NPOS     25
#define KTOT     800
#define MT       64       // nodes per block (4 waves x 16 nodes)
#define NTHREADS 256

typedef float    f32x4 __attribute__((ext_vector_type(4)));
typedef _Float16 f16x8 __attribute__((ext_vector_type(8)));

template<int N> using IC = std::integral_constant<int, N>;

typedef const __attribute__((address_space(1))) void GV;
typedef __attribute__((address_space(3))) void LV;

template<int N>
__device__ __forceinline__ void waitv_sb() {
    static_assert(N == 0 || N == 7 || N == 14, "bad vmcnt");
    if constexpr (N == 14)      asm volatile("s_waitcnt vmcnt(14)" ::: "memory");
    else if constexpr (N == 7)  asm volatile("s_waitcnt vmcnt(7)"  ::: "memory");
    else                        asm volatile("s_waitcnt vmcnt(0)"  ::: "memory");
    __builtin_amdgcn_sched_barrier(0);   // rule #18: fence MFMA/ds_read hoisting
}

// ---------------- precompute: xh = f16(x); wh = per-lane-swizzled f16 W ----------------
// wh layout: frag f=(p*4+nb), lane l, elem j:
//   wh[(f*64+l)*8+j] = W[16*nb+(l&15)][p*32+(l>>4)*8+j]
__global__ void cvt_kernel(const float* __restrict__ x, const float* __restrict__ W,
                           _Float16* __restrict__ xh, _Float16* __restrict__ wh) {
    int tid = blockIdx.x * blockDim.x + threadIdx.x;
    int stride = gridDim.x * blockDim.x;
    const int nx8 = NNODES * INF / 8;
    const f32x4* x4 = (const f32x4*)x;
    f16x8* xh8 = (f16x8*)xh;
    for (int j = tid; j < nx8; j += stride) {
        f32x4 a = x4[2*j], b = x4[2*j+1];
        f16x8 o;
        #pragma unroll
        for (int k = 0; k < 4; ++k) { o[k] = (_Float16)a[k]; o[4+k] = (_Float16)b[k]; }
        xh8[j] = o;
    }
    f16x8* wh8 = (f16x8*)wh;
    for (int t = tid; t < NPOS * 4 * 64; t += stride) {
        const int l  = t & 63;
        const int nb = (t >> 6) & 3;
        const int p  = t >> 8;
        const int row = 16*nb + (l & 15);
        const int kb  = p*32 + (l >> 4)*8;
        const float* src = W + row * KTOT + kb;
        f16x8 o;
        #pragma unroll
        for (int j = 0; j < 8; ++j) o[j] = (_Float16)src[j];
        wh8[t] = o;
    }
}

// ---------------- fused gather + MFMA: LDS-bounced gather pipeline ----------------
__launch_bounds__(NTHREADS, 2)
__global__ void conv_mfma(const int* __restrict__ nidx, const float* __restrict__ nwt,
                          const _Float16* __restrict__ xh, const _Float16* __restrict__ wh,
                          const float* __restrict__ bias, float* __restrict__ out) {
    __shared__ int      idxs[MT * 75];                    // 19200 B
    __shared__ _Float16 wtsl[MT * 76];                    // 9728 B
    __shared__ __align__(16) _Float16 feat[4][4][3][512]; // 49152 B: [wave][slot][vert][lane*8]

    const int tid = threadIdx.x;
    const int blk = blockIdx.x;

    // stage idx + f16 weights, coalesced; zero-fill past NNODES
    {
        const long gbase = (long)blk * (MT * 75);
        const long tot   = (long)NNODES * 75;
        #pragma unroll
        for (int it = 0; it < (MT * 75 + NTHREADS - 1) / NTHREADS; ++it) {
            int i = tid + it * NTHREADS;
            if (i < MT * 75) {
                long g = gbase + i;
                bool ok = g < tot;
                int n = i / 75, t = i % 75;
                idxs[i] = ok ? nidx[g] : 0;
                wtsl[n * 76 + t] = ok ? (_Float16)nwt[g] : (_Float16)0.0f;
            }
        }
    }

    const int lane = tid & 63;
    const int wave = tid >> 6;
    const int arow = lane & 15;       // node within wave's 16
    const int kgrp = lane >> 4;       // channel octet
    const int irow = (wave * 16 + arow) * 75;
    const int wrow = (wave * 16 + arow) * 76;
    const int node0 = blk * MT + wave * 16;
    const _Float16* xg  = xh + kgrp * 8;
    const char*     whl = (const char*)wh + (size_t)lane * 16;  // +p*4096 +nb*1024

    __syncthreads();

    f32x4 acc[4] = {{0,0,0,0},{0,0,0,0},{0,0,0,0},{0,0,0,0}};
    f16x8 bw[4][4];   // B-frag ring, statically indexed (full unroll)

    // one bundle = 3 LDS-DMA gathers + 4 asm B-loads = 7 vmem, order pinned
    auto ISSUE = [&](auto pc) {
        constexpr int p = decltype(pc)::value;
        constexpr int s = p & 3;
        #pragma unroll
        for (int v = 0; v < 3; ++v) {
            const int idx = idxs[irow + p * 3 + v];
            const _Float16* src = xg + (long)idx * INF;
            __builtin_amdgcn_global_load_lds((GV*)src, (LV*)(&feat[wave][s][v][0]), 16, 0, 0);
        }
        const char* a = whl + p * 4096;
        asm volatile(
            "global_load_dwordx4 %0, %4, off\n\t"
            "global_load_dwordx4 %1, %4, off offset:1024\n\t"
            "global_load_dwordx4 %2, %4, off offset:2048\n\t"
            "global_load_dwordx4 %3, %4, off offset:3072"
            : "=&v"(bw[s][0]), "=&v"(bw[s][1]), "=&v"(bw[s][2]), "=&v"(bw[s][3])
            : "v"(a)
            : "memory");
        __builtin_amdgcn_sched_barrier(0);
    };

    auto STEP = [&](auto pc) {
        constexpr int p = decltype(pc)::value;
        waitv_sb<(p <= 22) ? 14 : ((p == 23) ? 7 : 0)>();   // bundle p fully retired
        constexpr int s = p & 3;
        const f16x8 v0 = *(const f16x8*)&feat[wave][s][0][lane * 8];
        const f16x8 v1 = *(const f16x8*)&feat[wave][s][1][lane * 8];
        const f16x8 v2 = *(const f16x8*)&feat[wave][s][2][lane * 8];
        const _Float16 w0 = wtsl[wrow + p * 3 + 0];
        const _Float16 w1 = wtsl[wrow + p * 3 + 1];
        const _Float16 w2 = wtsl[wrow + p * 3 + 2];
        const f16x8 af = v0 * w0 + v1 * w1 + v2 * w2;
        #pragma unroll
        for (int nb = 0; nb < 4; ++nb)
            acc[nb] = __builtin_amdgcn_mfma_f32_16x16x32_f16(bw[s][nb], af, acc[nb], 0, 0, 0);
        __builtin_amdgcn_sched_barrier(0);
        if constexpr (p + 3 < NPOS) ISSUE(IC<p + 3>{});
    };

    ISSUE(IC<0>{}); ISSUE(IC<1>{}); ISSUE(IC<2>{});   // 21 vmem in flight

    STEP(IC<0>{});  STEP(IC<1>{});  STEP(IC<2>{});  STEP(IC<3>{});  STEP(IC<4>{});
    STEP(IC<5>{});  STEP(IC<6>{});  STEP(IC<7>{});  STEP(IC<8>{});  STEP(IC<9>{});
    STEP(IC<10>{}); STEP(IC<11>{}); STEP(IC<12>{}); STEP(IC<13>{}); STEP(IC<14>{});
    STEP(IC<15>{}); STEP(IC<16>{}); STEP(IC<17>{}); STEP(IC<18>{}); STEP(IC<19>{});
    STEP(IC<20>{}); STEP(IC<21>{}); STEP(IC<22>{}); STEP(IC<23>{}); STEP(IC<24>{});

    // epilogue: swapped-operand D=[outcol][node] (verified rounds 1-4 lineage):
    // col(lane&15)=node, rows 4*kgrp+r = outcol -> f32x4 store per nb
    const int node = node0 + arow;
    if (node < NNODES) {
        #pragma unroll
        for (int nb = 0; nb < 4; ++nb) {
            const int cb = 16*nb + 4*kgrp;
            const f32x4 b4 = *(const f32x4*)(bias + cb);
            f32x4 o;
            #pragma unroll
            for (int r = 0; r < 4; ++r) o[r] = acc[nb][r] + b4[r];
            *(f32x4*)(out + (long)node * OUTF + cb) = o;
        }
    }
}

// ---------------- safety fallback (no workspace needed), fp32 ----------------
__global__ void conv_fallback(const float* __restrict__ x, const int* __restrict__ nidx,
                              const float* __restrict__ nwt, const float* __restrict__ W,
                              const float* __restrict__ bias, float* __restrict__ out) {
    __shared__ float feat[KTOT];
    const int n = blockIdx.x;
    const int t = threadIdx.x;   // 64
    for (int e = t; e < KTOT; e += 64) {
        const int p = e >> 5, c = e & 31;
        const int ib = n * 75 + p * 3;
        float a = 0.0f;
        #pragma unroll
        for (int v = 0; v < 3; ++v)
            a += nwt[ib+v] * x[nidx[ib+v] * INF + c];
        feat[e] = a;
    }
    __syncthreads();
    float a = bias[t];
    const float* wr = W + t * KTOT;
    for (int k = 0; k < KTOT; ++k) a += feat[k] * wr[k];
    out[(long)n * OUTF + t] = a;
}

extern "C" void kernel_launch(void* const* d_in, const int* in_sizes, int n_in,
                              void* d_out, int out_size, void* d_ws, size_t ws_size,
                              hipStream_t stream) {
    const float* x    = (const float*)d_in[0];
    const int*   nidx = (const int*)  d_in[1];
    const float* nwt  = (const float*)d_in[2];
    const float* W    = (const float*)d_in[3];
    const float* bias = (const float*)d_in[4];
    float* out = (float*)d_out;

    const size_t need = (size_t)NNODES * INF * 2 + (size_t)NPOS * 4 * 64 * 8 * 2;
    if (ws_size < need) {
        conv_fallback<<<NNODES, 64, 0, stream>>>(x, nidx, nwt, W, bias, out);
        return;
    }

    _Float16* xh = (_Float16*)d_ws;
    _Float16* wh = xh + (size_t)NNODES * INF;

    cvt_kernel<<<1024, NTHREADS, 0, stream>>>(x, W, xh, wh);
    const int nblocks = (NNODES + MT - 1) / MT;   // 2561
    conv_mfma<<<nblocks, NTHREADS, 0, stream>>>(nidx, nwt, xh, wh, bias, out);
}